// Round 8
// baseline (358.460 us; speedup 1.0000x reference)
//
#include <hip/hip_runtime.h>
#include <math.h>

#define EPSF 1e-15f
#define MAX_ATANH (1.0f - 1e-5f)
#define ATT 16

#define LOG_NPB 10                 // nodes per bucket = 1024
#define NPB (1 << LOG_NPB)
#define MAXB 2048                  // max buckets (V <= 2^21)

// score table: s(vx, vy) on [-6.25, 6.25]^2, 512x512, bilinear
#define TDIM 512
#define TSPAN 12.5f
#define TSTEP (TSPAN / (float)(TDIM - 1))
#define TSCALE ((float)(TDIM - 1) / TSPAN)
#define TOFF (6.25f * TSCALE)

// native clang vector types — required by __builtin_nontemporal_load/store
typedef int    vint4  __attribute__((ext_vector_type(4)));
typedef unsigned vuint2 __attribute__((ext_vector_type(2)));
typedef float  vfloat2 __attribute__((ext_vector_type(2)));

// ---- fast branch-free transcendentals --------------------------------------
__device__ __forceinline__ float fast_atanh(float z) {
    return 0.5f * __logf(__fdividef(1.0f + z, 1.0f - z));
}
__device__ __forceinline__ float fast_tanh(float z) {
    return 1.0f - __fdividef(2.0f, __expf(2.0f * z) + 1.0f);
}
__device__ __forceinline__ float gelu_exact(float u) {
    return 0.5f * u * (1.0f + erff(u * 0.70710678118654752f));
}

// ---------------- K0: build score table (exact erf; ~µs) -------------------
__global__ void __launch_bounds__(256) build_table_kernel(
        const float* __restrict__ W1, const float* __restrict__ b1,
        const float* __restrict__ W2, float2* __restrict__ tab) {
    const int idx = blockIdx.x * 256 + threadIdx.x;
    if (idx >= TDIM * TDIM) return;
    const int iy = idx >> 9;
    const int ix = idx & (TDIM - 1);
    const float vy  = fmaf((float)iy, TSTEP, -6.25f);
    const float vx0 = fmaf((float)ix, TSTEP, -6.25f);
    const float vx1 = fmaf((float)min(ix + 1, TDIM - 1), TSTEP, -6.25f);
    float s0 = 0.0f, s1 = 0.0f;
    #pragma unroll
    for (int k = 0; k < ATT; ++k) {
        const float w1x = W1[k], w1y = W1[ATT + k], bb = b1[k], w2 = W2[k];
        s0 = fmaf(gelu_exact(fmaf(vx0, w1x, fmaf(vy, w1y, bb))), w2, s0);
        s1 = fmaf(gelu_exact(fmaf(vx1, w1x, fmaf(vy, w1y, bb))), w2, s1);
    }
    tab[idx] = make_float2(s0, s1);
}

// ---------------- K1: per-block bucket histogram ---------------------------
__global__ void __launch_bounds__(256) hist_kernel(const int* __restrict__ row,
                                                   int E, int B,
                                                   unsigned* __restrict__ counts /*[B][nblk]*/) {
    __shared__ unsigned h[MAXB];
    for (int i = threadIdx.x; i < B; i += 256) h[i] = 0u;
    __syncthreads();
    const int T = gridDim.x * 256;
    const int nv = E >> 2;
    const vint4* row4 = (const vint4*)row;
    for (int i = blockIdx.x * 256 + threadIdx.x; i < nv; i += T) {
        const vint4 r = __builtin_nontemporal_load(&row4[i]);
        atomicAdd(&h[((unsigned)r.x) >> LOG_NPB], 1u);
        atomicAdd(&h[((unsigned)r.y) >> LOG_NPB], 1u);
        atomicAdd(&h[((unsigned)r.z) >> LOG_NPB], 1u);
        atomicAdd(&h[((unsigned)r.w) >> LOG_NPB], 1u);
    }
    for (int e = (nv << 2) + blockIdx.x * 256 + threadIdx.x; e < E; e += T)
        atomicAdd(&h[((unsigned)row[e]) >> LOG_NPB], 1u);
    __syncthreads();
    for (int i = threadIdx.x; i < B; i += 256)
        counts[(size_t)i * gridDim.x + blockIdx.x] = h[i];
}

// ---------------- K2a: exclusive scan of each bucket's nblk counts ---------
// K = nblk/256 elems per thread, compile-time.
template<int K>
__global__ void __launch_bounds__(256) scan_blocks_kernel(const unsigned* __restrict__ counts,
                                                          unsigned* __restrict__ within,
                                                          unsigned* __restrict__ totals,
                                                          int nblk) {
    const int b = blockIdx.x;
    const unsigned* src = counts + (size_t)b * nblk;
    unsigned* dst = within + (size_t)b * nblk;
    __shared__ unsigned s[256];
    unsigned vals[K];
    unsigned sum = 0u;
    if constexpr (K == 2) {
        const uint2 v = ((const uint2*)src)[threadIdx.x];
        vals[0] = v.x; vals[1] = v.y;
    } else if constexpr (K == 4) {
        const uint4 v = ((const uint4*)src)[threadIdx.x];
        vals[0] = v.x; vals[1] = v.y; vals[2] = v.z; vals[3] = v.w;
    } else {
        const uint4 va = ((const uint4*)src)[threadIdx.x * 2];
        const uint4 vb = ((const uint4*)src)[threadIdx.x * 2 + 1];
        vals[0] = va.x; vals[1] = va.y; vals[2] = va.z; vals[3] = va.w;
        vals[4] = vb.x; vals[5] = vb.y; vals[6] = vb.z; vals[7] = vb.w;
    }
    #pragma unroll
    for (int k = 0; k < K; ++k) sum += vals[k];
    s[threadIdx.x] = sum;
    __syncthreads();
    for (int off = 1; off < 256; off <<= 1) {
        unsigned t = (threadIdx.x >= off) ? s[threadIdx.x - off] : 0u;
        __syncthreads();
        s[threadIdx.x] += t;
        __syncthreads();
    }
    unsigned run = (threadIdx.x > 0) ? s[threadIdx.x - 1] : 0u;
    unsigned outv[K];
    #pragma unroll
    for (int k = 0; k < K; ++k) { outv[k] = run; run += vals[k]; }
    if constexpr (K == 2) {
        uint2 o; o.x = outv[0]; o.y = outv[1];
        ((uint2*)dst)[threadIdx.x] = o;
    } else if constexpr (K == 4) {
        uint4 o; o.x = outv[0]; o.y = outv[1]; o.z = outv[2]; o.w = outv[3];
        ((uint4*)dst)[threadIdx.x] = o;
    } else {
        uint4 oa, ob;
        oa.x = outv[0]; oa.y = outv[1]; oa.z = outv[2]; oa.w = outv[3];
        ob.x = outv[4]; ob.y = outv[5]; ob.z = outv[6]; ob.w = outv[7];
        ((uint4*)dst)[threadIdx.x * 2]     = oa;
        ((uint4*)dst)[threadIdx.x * 2 + 1] = ob;
    }
    if (threadIdx.x == 255) totals[b] = s[255];
}

// ---------------- K2b: exclusive scan of bucket totals -> base[B+1] --------
__global__ void __launch_bounds__(256) scan_totals_kernel(const unsigned* __restrict__ totals,
                                                          unsigned* __restrict__ base, int B) {
    __shared__ unsigned s[256];
    unsigned vals[8];
    const int i0 = threadIdx.x * 8;
    unsigned sum = 0u;
    #pragma unroll
    for (int k = 0; k < 8; ++k) {
        vals[k] = (i0 + k < B) ? totals[i0 + k] : 0u;
        sum += vals[k];
    }
    s[threadIdx.x] = sum;
    __syncthreads();
    for (int off = 1; off < 256; off <<= 1) {
        unsigned t = (threadIdx.x >= off) ? s[threadIdx.x - off] : 0u;
        __syncthreads();
        s[threadIdx.x] += t;
        __syncthreads();
    }
    unsigned b0 = (threadIdx.x > 0) ? s[threadIdx.x - 1] : 0u;
    #pragma unroll
    for (int k = 0; k < 8; ++k) {
        if (i0 + k < B) base[i0 + k] = b0;
        b0 += vals[k];
    }
    if (threadIdx.x == 255) base[B] = s[255];
}

// ---------------- K3: scatter edges into bucket-sorted payload -------------
// payload word: (lrow:10 << 21) | col:21   (V <= 2^21)
__global__ void __launch_bounds__(256) scatter_kernel(const int* __restrict__ row,
                                                      const int* __restrict__ col,
                                                      int E, int B,
                                                      const unsigned* __restrict__ base,
                                                      const unsigned* __restrict__ within,
                                                      unsigned* __restrict__ payload) {
    __shared__ unsigned cur[MAXB];
    const int nblk = gridDim.x;
    for (int i = threadIdx.x; i < B; i += 256)
        cur[i] = base[i] + within[(size_t)i * nblk + blockIdx.x];
    __syncthreads();
    const int T = nblk * 256;
    const int nv = E >> 2;
    const vint4* row4 = (const vint4*)row;
    const vint4* col4 = (const vint4*)col;
    for (int i = blockIdx.x * 256 + threadIdx.x; i < nv; i += T) {
        const vint4 r = __builtin_nontemporal_load(&row4[i]);
        const vint4 c = __builtin_nontemporal_load(&col4[i]);
        {
            const unsigned rr = (unsigned)r.x;
            const unsigned pos = atomicAdd(&cur[rr >> LOG_NPB], 1u);
            payload[pos] = ((rr & (NPB - 1)) << 21) | (unsigned)c.x;
        }
        {
            const unsigned rr = (unsigned)r.y;
            const unsigned pos = atomicAdd(&cur[rr >> LOG_NPB], 1u);
            payload[pos] = ((rr & (NPB - 1)) << 21) | (unsigned)c.y;
        }
        {
            const unsigned rr = (unsigned)r.z;
            const unsigned pos = atomicAdd(&cur[rr >> LOG_NPB], 1u);
            payload[pos] = ((rr & (NPB - 1)) << 21) | (unsigned)c.z;
        }
        {
            const unsigned rr = (unsigned)r.w;
            const unsigned pos = atomicAdd(&cur[rr >> LOG_NPB], 1u);
            payload[pos] = ((rr & (NPB - 1)) << 21) | (unsigned)c.w;
        }
    }
    for (int e = (nv << 2) + blockIdx.x * 256 + threadIdx.x; e < E; e += T) {
        const unsigned rr = (unsigned)row[e];
        const unsigned pos = atomicAdd(&cur[rr >> LOG_NPB], 1u);
        payload[pos] = ((rr & (NPB - 1)) << 21) | (unsigned)col[e];
    }
}

// ---------------- K4: per-bucket LDS accumulate + node epilogue ------------
__device__ __forceinline__ void edge_math(unsigned p,
        const float2* __restrict__ x, const float2* __restrict__ tab,
        const float2* sxi, float* sden, float* smx, float* smy) {
    const unsigned lrow = p >> 21;
    const unsigned c = p & 0x1FFFFFu;
    const float2 xj = x[c];                      // random gather, L2/LLC
    const float2 xi = sxi[lrow];                 // LDS

    const float ax = -xi.x, ay = -xi.y;
    const float bx = xj.x,  by = xj.y;
    const float a2 = ax * ax + ay * ay;
    const float b2 = bx * bx + by * by;
    const float ab = ax * bx + ay * by;
    const float ca = 1.0f + 2.0f * ab + b2;
    const float cb = 1.0f - a2;
    const float dn = fmaxf(1.0f + 2.0f * ab + a2 * b2, EPSF);
    const float rdn = __fdividef(1.0f, dn);
    const float subx = (ca * ax + cb * bx) * rdn;
    const float suby = (ca * ay + cb * by) * rdn;

    const float n = fmaxf(sqrtf(subx * subx + suby * suby), EPSF);
    const float M = fmaxf(1.0f - (xi.x * xi.x + xi.y * xi.y), EPSF);
    const float scl = M * fast_atanh(fminf(n, MAX_ATANH)) * __fdividef(1.0f, n);
    const float vx = scl * subx;
    const float vy = scl * suby;

    float tx = fmaf(vx, TSCALE, TOFF);
    float ty = fmaf(vy, TSCALE, TOFF);
    tx = fminf(fmaxf(tx, 0.0f), 510.999f);
    ty = fminf(fmaxf(ty, 0.0f), 510.999f);
    const int ix = (int)tx;
    const int iy = (int)ty;
    const float fx = tx - (float)ix;
    const float fy = ty - (float)iy;
    const int baseIdx = (iy << 9) + ix;
    const float2 r0 = tab[baseIdx];
    const float2 r1 = tab[baseIdx + TDIM];
    const float s0 = fmaf(fx, r0.y - r0.x, r0.x);
    const float s1 = fmaf(fx, r1.y - r1.x, r1.x);
    const float s  = fmaf(fy, s1 - s0, s0);

    const float ee = __expf(s);
    atomicAdd(&sden[lrow], ee);
    atomicAdd(&smx[lrow], ee * vx);
    atomicAdd(&smy[lrow], ee * vy);
}

__global__ void __launch_bounds__(512, 8) bucket_reduce_kernel(
        const float2* __restrict__ x,
        const float2* __restrict__ tab,
        const unsigned* __restrict__ base,
        const unsigned* __restrict__ payload,
        const int* __restrict__ depth,
        const float* __restrict__ depth_scale,
        const float* __restrict__ depth_theta,
        const float* __restrict__ eta_p,
        float2* __restrict__ out, int V) {
    __shared__ float  sden[NPB];
    __shared__ float  smx[NPB];
    __shared__ float  smy[NPB];
    __shared__ float2 sxi[NPB];
    const int b = blockIdx.x;
    const int nodeBase = b << LOG_NPB;
    for (int i = threadIdx.x; i < NPB; i += 512) {
        sden[i] = 0.f; smx[i] = 0.f; smy[i] = 0.f;
        sxi[i] = x[nodeBase + i];
    }
    __syncthreads();

    const unsigned e0 = base[b], e1 = base[b + 1];
    unsigned s0 = e0;
    if ((s0 & 1u) && s0 < e1) {                 // head for 8B alignment
        if (threadIdx.x == 0)
            edge_math(payload[s0], x, tab, sxi, sden, smx, smy);
        ++s0;
    }
    const unsigned cnt = (e1 > s0) ? (e1 - s0) : 0u;
    const unsigned pairs = cnt >> 1;
    // paired loop: coalesced uint2 payload loads (nontemporal — single use),
    // two independent xj gathers in flight per thread per iteration.
    const vuint2* pay2 = (const vuint2*)(payload + s0);
    for (unsigned k = threadIdx.x; k < pairs; k += 512) {
        const vuint2 pp = __builtin_nontemporal_load(&pay2[k]);
        edge_math(pp.x, x, tab, sxi, sden, smx, smy);
        edge_math(pp.y, x, tab, sxi, sden, smx, smy);
    }
    if ((cnt & 1u) && threadIdx.x == 0)         // tail
        edge_math(payload[s0 + (pairs << 1)], x, tab, sxi, sden, smx, smy);
    __syncthreads();

    // node epilogue: normalize, depth mixer, exp-map
    const float eta = eta_p[0];
    for (int i = threadIdx.x; i < NPB; i += 512) {
        const int v = nodeBase + i;
        if (v >= V) break;
        const float rdv = __fdividef(1.0f, fmaxf(sden[i], EPSF));
        const float mx = smx[i] * rdv;
        const float my = smy[i] * rdv;

        const int d = min(depth[v], 511);
        const float k   = depth_scale[d];
        const float ang = depth_theta[d];
        const float cs = __cosf(ang), sn = __sinf(ang);
        const float m0 = eta * (k * (cs * mx - sn * my));
        const float m1 = eta * (k * (sn * mx + cs * my));

        const float2 xi = sxi[i];

        const float n = fmaxf(sqrtf(m0 * m0 + m1 * m1), EPSF);
        const float M = fmaxf(1.0f - (xi.x * xi.x + xi.y * xi.y), EPSF);
        const float t = fast_tanh(__fdividef(n, M));
        const float tn = t * __fdividef(1.0f, n);
        const float bx = tn * m0;
        const float by = tn * m1;

        const float a2 = xi.x * xi.x + xi.y * xi.y;
        const float b2 = bx * bx + by * by;
        const float ab = xi.x * bx + xi.y * by;
        const float ca = 1.0f + 2.0f * ab + b2;
        const float cb = 1.0f - a2;
        const float dn = fmaxf(1.0f + 2.0f * ab + a2 * b2, EPSF);
        const float rdn = __fdividef(1.0f, dn);

        vfloat2 o;
        o.x = (ca * xi.x + cb * bx) * rdn;
        o.y = (ca * xi.y + cb * by) * rdn;
        __builtin_nontemporal_store(o, (vfloat2*)&out[v]);
    }
}

extern "C" void kernel_launch(void* const* d_in, const int* in_sizes, int n_in,
                              void* d_out, int out_size, void* d_ws, size_t ws_size,
                              hipStream_t stream) {
    const float2* x          = (const float2*)d_in[0];
    const float*  W1         = (const float*)d_in[1];
    const float*  b1         = (const float*)d_in[2];
    const float*  W2         = (const float*)d_in[3];
    const float*  eta        = (const float*)d_in[4];
    const float*  dscale     = (const float*)d_in[5];
    const float*  dtheta     = (const float*)d_in[6];
    const int*    edge_index = (const int*)d_in[7];
    const int*    depth      = (const int*)d_in[8];

    const int V = in_sizes[0] / 2;
    const int E = in_sizes[7] / 2;
    const int B = (V + NPB - 1) >> LOG_NPB;       // 2048 for V = 2^21

    const int* row = edge_index;
    const int* col = edge_index + E;

    // pick nblk (= hist/scatter grid) to maximize occupancy within ws_size:
    // need = (E + 2*B*nblk + 2B + 2) u32 words
    auto need = [&](int nblk) -> size_t {
        return ((size_t)E + 2 * (size_t)B * nblk + 2 * (size_t)B + 2) * 4;
    };
    int nblk = 512;
    if (ws_size >= need(2048)) nblk = 2048;
    else if (ws_size >= need(1024)) nblk = 1024;

    unsigned* payload = (unsigned*)d_ws;
    unsigned* counts  = payload + E;
    unsigned* within  = counts + (size_t)B * nblk;
    unsigned* totals  = within + (size_t)B * nblk;
    unsigned* base    = totals + B;
    float2*   tab     = (float2*)within;          // within dead after scatter

    hist_kernel<<<nblk, 256, 0, stream>>>(row, E, B, counts);
    if (nblk == 2048)
        scan_blocks_kernel<8><<<B, 256, 0, stream>>>(counts, within, totals, nblk);
    else if (nblk == 1024)
        scan_blocks_kernel<4><<<B, 256, 0, stream>>>(counts, within, totals, nblk);
    else
        scan_blocks_kernel<2><<<B, 256, 0, stream>>>(counts, within, totals, nblk);
    scan_totals_kernel<<<1, 256, 0, stream>>>(totals, base, B);
    scatter_kernel<<<nblk, 256, 0, stream>>>(row, col, E, B, base, within, payload);
    build_table_kernel<<<(TDIM * TDIM) / 256, 256, 0, stream>>>(W1, b1, W2, tab);
    bucket_reduce_kernel<<<B, 512, 0, stream>>>(x, tab, base, payload,
                                                depth, dscale, dtheta, eta,
                                                (float2*)d_out, V);
}

// Round 9
// 270.049 us; speedup vs baseline: 1.3274x; 1.3274x over previous
//
#include <hip/hip_runtime.h>
#include <math.h>

#define EPSF 1e-15f
#define MAX_ATANH (1.0f - 1e-5f)
#define ATT 16

#define LOG_NPB 11                 // nodes per bucket = 2048
#define NPB (1 << LOG_NPB)
#define MAXB 1024                  // max buckets (V <= 2^21)
#define NBLK 512                   // blocks in hist/scatter kernels

// score table: s(vx, vy) on [-6.25, 6.25]^2, 512x512, bilinear
#define TDIM 512
#define TSPAN 12.5f
#define TSTEP (TSPAN / (float)(TDIM - 1))
#define TSCALE ((float)(TDIM - 1) / TSPAN)
#define TOFF (6.25f * TSCALE)

// ---- fast branch-free transcendentals --------------------------------------
__device__ __forceinline__ float fast_atanh(float z) {
    return 0.5f * __logf(__fdividef(1.0f + z, 1.0f - z));
}
__device__ __forceinline__ float fast_tanh(float z) {
    return 1.0f - __fdividef(2.0f, __expf(2.0f * z) + 1.0f);
}
__device__ __forceinline__ float gelu_exact(float u) {
    return 0.5f * u * (1.0f + erff(u * 0.70710678118654752f));
}

// ---------------- K0: build score table (exact erf; ~µs) -------------------
__global__ void __launch_bounds__(256) build_table_kernel(
        const float* __restrict__ W1, const float* __restrict__ b1,
        const float* __restrict__ W2, float2* __restrict__ tab) {
    const int idx = blockIdx.x * 256 + threadIdx.x;
    if (idx >= TDIM * TDIM) return;
    const int iy = idx >> 9;
    const int ix = idx & (TDIM - 1);
    const float vy  = fmaf((float)iy, TSTEP, -6.25f);
    const float vx0 = fmaf((float)ix, TSTEP, -6.25f);
    const float vx1 = fmaf((float)min(ix + 1, TDIM - 1), TSTEP, -6.25f);
    float s0 = 0.0f, s1 = 0.0f;
    #pragma unroll
    for (int k = 0; k < ATT; ++k) {
        const float w1x = W1[k], w1y = W1[ATT + k], bb = b1[k], w2 = W2[k];
        s0 = fmaf(gelu_exact(fmaf(vx0, w1x, fmaf(vy, w1y, bb))), w2, s0);
        s1 = fmaf(gelu_exact(fmaf(vx1, w1x, fmaf(vy, w1y, bb))), w2, s1);
    }
    tab[idx] = make_float2(s0, s1);
}

// ---------------- K1: per-block bucket histogram ---------------------------
__global__ void __launch_bounds__(256) hist_kernel(const int* __restrict__ row,
                                                   int E, int B,
                                                   unsigned* __restrict__ counts /*[B][NBLK]*/) {
    __shared__ unsigned h[MAXB];
    for (int i = threadIdx.x; i < B; i += 256) h[i] = 0u;
    __syncthreads();
    const int T = gridDim.x * 256;
    const int nv = E >> 2;
    const int4* row4 = (const int4*)row;
    for (int i = blockIdx.x * 256 + threadIdx.x; i < nv; i += T) {
        const int4 r = row4[i];
        atomicAdd(&h[((unsigned)r.x) >> LOG_NPB], 1u);
        atomicAdd(&h[((unsigned)r.y) >> LOG_NPB], 1u);
        atomicAdd(&h[((unsigned)r.z) >> LOG_NPB], 1u);
        atomicAdd(&h[((unsigned)r.w) >> LOG_NPB], 1u);
    }
    for (int e = (nv << 2) + blockIdx.x * 256 + threadIdx.x; e < E; e += T)
        atomicAdd(&h[((unsigned)row[e]) >> LOG_NPB], 1u);
    __syncthreads();
    for (int i = threadIdx.x; i < B; i += 256)
        counts[(size_t)i * gridDim.x + blockIdx.x] = h[i];
}

// ---------------- K2a: exclusive scan of each bucket's NBLK counts ---------
// NBLK = 512, 256 threads, exactly 2 elems/thread.
__global__ void __launch_bounds__(256) scan_blocks_kernel(const unsigned* __restrict__ counts,
                                                          unsigned* __restrict__ within,
                                                          unsigned* __restrict__ totals) {
    const int b = blockIdx.x;
    const unsigned* src = counts + (size_t)b * NBLK;
    unsigned* dst = within + (size_t)b * NBLK;
    __shared__ unsigned s[256];
    unsigned v0, v1;
    {
        const uint2 v = ((const uint2*)src)[threadIdx.x];
        v0 = v.x; v1 = v.y;
    }
    s[threadIdx.x] = v0 + v1;
    __syncthreads();
    for (int off = 1; off < 256; off <<= 1) {
        unsigned t = (threadIdx.x >= off) ? s[threadIdx.x - off] : 0u;
        __syncthreads();
        s[threadIdx.x] += t;
        __syncthreads();
    }
    unsigned base = (threadIdx.x > 0) ? s[threadIdx.x - 1] : 0u;
    uint2 o;
    o.x = base; o.y = base + v0;
    ((uint2*)dst)[threadIdx.x] = o;
    if (threadIdx.x == 255) totals[b] = s[255];
}

// ---------------- K2b: exclusive scan of bucket totals -> base[B+1] --------
__global__ void __launch_bounds__(256) scan_totals_kernel(const unsigned* __restrict__ totals,
                                                          unsigned* __restrict__ base, int B) {
    __shared__ unsigned s[256];
    unsigned vals[8];
    const int i0 = threadIdx.x * 8;
    unsigned sum = 0u;
    #pragma unroll
    for (int k = 0; k < 8; ++k) {
        vals[k] = (i0 + k < B) ? totals[i0 + k] : 0u;
        sum += vals[k];
    }
    s[threadIdx.x] = sum;
    __syncthreads();
    for (int off = 1; off < 256; off <<= 1) {
        unsigned t = (threadIdx.x >= off) ? s[threadIdx.x - off] : 0u;
        __syncthreads();
        s[threadIdx.x] += t;
        __syncthreads();
    }
    unsigned b0 = (threadIdx.x > 0) ? s[threadIdx.x - 1] : 0u;
    #pragma unroll
    for (int k = 0; k < 8; ++k) {
        if (i0 + k < B) base[i0 + k] = b0;
        b0 += vals[k];
    }
    if (threadIdx.x == 255) base[B] = s[255];
}

// ---------------- K3: scatter edges into bucket-sorted payload -------------
// payload word: (lrow:11 << 21) | col:21   (V <= 2^21)
__global__ void __launch_bounds__(256) scatter_kernel(const int* __restrict__ row,
                                                      const int* __restrict__ col,
                                                      int E, int B,
                                                      const unsigned* __restrict__ base,
                                                      const unsigned* __restrict__ within,
                                                      unsigned* __restrict__ payload) {
    __shared__ unsigned cur[MAXB];
    const int nblk = gridDim.x;
    for (int i = threadIdx.x; i < B; i += 256)
        cur[i] = base[i] + within[(size_t)i * nblk + blockIdx.x];
    __syncthreads();
    const int T = nblk * 256;
    const int nv = E >> 2;
    const int4* row4 = (const int4*)row;
    const int4* col4 = (const int4*)col;
    for (int i = blockIdx.x * 256 + threadIdx.x; i < nv; i += T) {
        const int4 r = row4[i];
        const int4 c = col4[i];
        {
            const unsigned rr = (unsigned)r.x;
            const unsigned pos = atomicAdd(&cur[rr >> LOG_NPB], 1u);
            payload[pos] = ((rr & (NPB - 1)) << 21) | (unsigned)c.x;
        }
        {
            const unsigned rr = (unsigned)r.y;
            const unsigned pos = atomicAdd(&cur[rr >> LOG_NPB], 1u);
            payload[pos] = ((rr & (NPB - 1)) << 21) | (unsigned)c.y;
        }
        {
            const unsigned rr = (unsigned)r.z;
            const unsigned pos = atomicAdd(&cur[rr >> LOG_NPB], 1u);
            payload[pos] = ((rr & (NPB - 1)) << 21) | (unsigned)c.z;
        }
        {
            const unsigned rr = (unsigned)r.w;
            const unsigned pos = atomicAdd(&cur[rr >> LOG_NPB], 1u);
            payload[pos] = ((rr & (NPB - 1)) << 21) | (unsigned)c.w;
        }
    }
    for (int e = (nv << 2) + blockIdx.x * 256 + threadIdx.x; e < E; e += T) {
        const unsigned rr = (unsigned)row[e];
        const unsigned pos = atomicAdd(&cur[rr >> LOG_NPB], 1u);
        payload[pos] = ((rr & (NPB - 1)) << 21) | (unsigned)col[e];
    }
}

// ---------------- K4: per-bucket LDS accumulate + node epilogue ------------
__device__ __forceinline__ void edge_compute(unsigned p, float2 xj,
        const float2* __restrict__ tab,
        const float2* sxi, float* sden, float* smx, float* smy) {
    const unsigned lrow = p >> 21;
    const float2 xi = sxi[lrow];                 // LDS

    const float ax = -xi.x, ay = -xi.y;
    const float bx = xj.x,  by = xj.y;
    const float a2 = ax * ax + ay * ay;
    const float b2 = bx * bx + by * by;
    const float ab = ax * bx + ay * by;
    const float ca = 1.0f + 2.0f * ab + b2;
    const float cb = 1.0f - a2;
    const float dn = fmaxf(1.0f + 2.0f * ab + a2 * b2, EPSF);
    const float rdn = __fdividef(1.0f, dn);
    const float subx = (ca * ax + cb * bx) * rdn;
    const float suby = (ca * ay + cb * by) * rdn;

    const float n = fmaxf(sqrtf(subx * subx + suby * suby), EPSF);
    const float M = fmaxf(1.0f - (xi.x * xi.x + xi.y * xi.y), EPSF);
    const float scl = M * fast_atanh(fminf(n, MAX_ATANH)) * __fdividef(1.0f, n);
    const float vx = scl * subx;
    const float vy = scl * suby;

    float tx = fmaf(vx, TSCALE, TOFF);
    float ty = fmaf(vy, TSCALE, TOFF);
    tx = fminf(fmaxf(tx, 0.0f), 510.999f);
    ty = fminf(fmaxf(ty, 0.0f), 510.999f);
    const int ix = (int)tx;
    const int iy = (int)ty;
    const float fx = tx - (float)ix;
    const float fy = ty - (float)iy;
    const int baseIdx = (iy << 9) + ix;
    const float2 r0 = tab[baseIdx];
    const float2 r1 = tab[baseIdx + TDIM];
    const float s0 = fmaf(fx, r0.y - r0.x, r0.x);
    const float s1 = fmaf(fx, r1.y - r1.x, r1.x);
    const float s  = fmaf(fy, s1 - s0, s0);

    const float ee = __expf(s);
    atomicAdd(&sden[lrow], ee);
    atomicAdd(&smx[lrow], ee * vx);
    atomicAdd(&smy[lrow], ee * vy);
}

__device__ __forceinline__ void edge_single(unsigned p,
        const float2* __restrict__ x, const float2* __restrict__ tab,
        const float2* sxi, float* sden, float* smx, float* smy) {
    edge_compute(p, x[p & 0x1FFFFFu], tab, sxi, sden, smx, smy);
}

__global__ void __launch_bounds__(512, 8) bucket_reduce_kernel(
        const float2* __restrict__ x,
        const float2* __restrict__ tab,
        const unsigned* __restrict__ base,
        const unsigned* __restrict__ payload,
        const int* __restrict__ depth,
        const float* __restrict__ depth_scale,
        const float* __restrict__ depth_theta,
        const float* __restrict__ eta_p,
        float2* __restrict__ out, int V) {
    __shared__ float  sden[NPB];
    __shared__ float  smx[NPB];
    __shared__ float  smy[NPB];
    __shared__ float2 sxi[NPB];
    const int b = blockIdx.x;
    const int nodeBase = b << LOG_NPB;
    for (int i = threadIdx.x; i < NPB; i += 512) {
        sden[i] = 0.f; smx[i] = 0.f; smy[i] = 0.f;
        sxi[i] = x[nodeBase + i];
    }
    __syncthreads();

    const unsigned e0 = base[b], e1 = base[b + 1];
    // head: align to 16B (4 words)
    unsigned s0 = e0;
    const unsigned head = min((4u - (s0 & 3u)) & 3u, e1 - s0);
    if (threadIdx.x < head)
        edge_single(payload[s0 + threadIdx.x], x, tab, sxi, sden, smx, smy);
    s0 += head;
    const unsigned cnt = e1 - s0;
    const unsigned quads = cnt >> 2;
    // quad loop: coalesced uint4 payload loads; 4 independent xj gathers
    // issued before any math (memory-level parallelism).
    const uint4* pay4 = (const uint4*)(payload + s0);
    for (unsigned k = threadIdx.x; k < quads; k += 512) {
        const uint4 pp = pay4[k];
        const float2 xj0 = x[pp.x & 0x1FFFFFu];
        const float2 xj1 = x[pp.y & 0x1FFFFFu];
        const float2 xj2 = x[pp.z & 0x1FFFFFu];
        const float2 xj3 = x[pp.w & 0x1FFFFFu];
        edge_compute(pp.x, xj0, tab, sxi, sden, smx, smy);
        edge_compute(pp.y, xj1, tab, sxi, sden, smx, smy);
        edge_compute(pp.z, xj2, tab, sxi, sden, smx, smy);
        edge_compute(pp.w, xj3, tab, sxi, sden, smx, smy);
    }
    const unsigned rem = cnt & 3u;
    if (threadIdx.x < rem)
        edge_single(payload[s0 + (quads << 2) + threadIdx.x], x, tab, sxi, sden, smx, smy);
    __syncthreads();

    // node epilogue: normalize, depth mixer, exp-map
    const float eta = eta_p[0];
    for (int i = threadIdx.x; i < NPB; i += 512) {
        const int v = nodeBase + i;
        if (v >= V) break;
        const float rdv = __fdividef(1.0f, fmaxf(sden[i], EPSF));
        const float mx = smx[i] * rdv;
        const float my = smy[i] * rdv;

        const int d = min(depth[v], 511);
        const float k   = depth_scale[d];
        const float ang = depth_theta[d];
        const float cs = __cosf(ang), sn = __sinf(ang);
        const float m0 = eta * (k * (cs * mx - sn * my));
        const float m1 = eta * (k * (sn * mx + cs * my));

        const float2 xi = sxi[i];

        const float n = fmaxf(sqrtf(m0 * m0 + m1 * m1), EPSF);
        const float M = fmaxf(1.0f - (xi.x * xi.x + xi.y * xi.y), EPSF);
        const float t = fast_tanh(__fdividef(n, M));
        const float tn = t * __fdividef(1.0f, n);
        const float bx = tn * m0;
        const float by = tn * m1;

        const float a2 = xi.x * xi.x + xi.y * xi.y;
        const float b2 = bx * bx + by * by;
        const float ab = xi.x * bx + xi.y * by;
        const float ca = 1.0f + 2.0f * ab + b2;
        const float cb = 1.0f - a2;
        const float dn = fmaxf(1.0f + 2.0f * ab + a2 * b2, EPSF);
        const float rdn = __fdividef(1.0f, dn);

        out[v] = make_float2((ca * xi.x + cb * bx) * rdn,
                             (ca * xi.y + cb * by) * rdn);
    }
}

extern "C" void kernel_launch(void* const* d_in, const int* in_sizes, int n_in,
                              void* d_out, int out_size, void* d_ws, size_t ws_size,
                              hipStream_t stream) {
    const float2* x          = (const float2*)d_in[0];
    const float*  W1         = (const float*)d_in[1];
    const float*  b1         = (const float*)d_in[2];
    const float*  W2         = (const float*)d_in[3];
    const float*  eta        = (const float*)d_in[4];
    const float*  dscale     = (const float*)d_in[5];
    const float*  dtheta     = (const float*)d_in[6];
    const int*    edge_index = (const int*)d_in[7];
    const int*    depth      = (const int*)d_in[8];

    const int V = in_sizes[0] / 2;
    const int E = in_sizes[7] / 2;
    const int B = (V + NPB - 1) >> LOG_NPB;       // 1024 for V = 2^21

    const int* row = edge_index;
    const int* col = edge_index + E;

    // workspace layout (all u32): payload[E] | counts[B*NBLK] | within[B*NBLK]
    //                             | totals[B] | base[B+1]
    // score table (2MB float2) reuses `within` (2MB), dead after scatter.
    unsigned* payload = (unsigned*)d_ws;
    unsigned* counts  = payload + E;
    unsigned* within  = counts + (size_t)B * NBLK;
    unsigned* totals  = within + (size_t)B * NBLK;
    unsigned* base    = totals + B;
    float2*   tab     = (float2*)within;

    hist_kernel<<<NBLK, 256, 0, stream>>>(row, E, B, counts);
    scan_blocks_kernel<<<B, 256, 0, stream>>>(counts, within, totals);
    scan_totals_kernel<<<1, 256, 0, stream>>>(totals, base, B);
    scatter_kernel<<<NBLK, 256, 0, stream>>>(row, col, E, B, base, within, payload);
    build_table_kernel<<<(TDIM * TDIM) / 256, 256, 0, stream>>>(W1, b1, W2, tab);
    bucket_reduce_kernel<<<B, 512, 0, stream>>>(x, tab, base, payload,
                                                depth, dscale, dtheta, eta,
                                                (float2*)d_out, V);
}

// Round 10
// 262.193 us; speedup vs baseline: 1.3672x; 1.0300x over previous
//
#include <hip/hip_runtime.h>
#include <math.h>

#define EPSF 1e-15f
#define MAX_ATANH (1.0f - 1e-5f)
#define ATT 16

#define LOG_NPB 11                 // nodes per bucket = 2048
#define NPB (1 << LOG_NPB)
#define MAXB 1024                  // max buckets (V <= 2^21)
#define NBLK 512                   // blocks in hist/scatter kernels

// score table: s(vx, vy) on [-6.25, 6.25]^2, 512x512, bilinear
#define TDIM 512
#define TSPAN 12.5f
#define TSTEP (TSPAN / (float)(TDIM - 1))
#define TSCALE ((float)(TDIM - 1) / TSPAN)
#define TOFF (6.25f * TSCALE)

// ---- fast branch-free transcendentals --------------------------------------
__device__ __forceinline__ float fast_atanh(float z) {
    return 0.5f * __logf(__fdividef(1.0f + z, 1.0f - z));
}
__device__ __forceinline__ float fast_tanh(float z) {
    return 1.0f - __fdividef(2.0f, __expf(2.0f * z) + 1.0f);
}
__device__ __forceinline__ float gelu_exact(float u) {
    return 0.5f * u * (1.0f + erff(u * 0.70710678118654752f));
}

// ---------------- K0: build score table (exact erf; ~µs) -------------------
__global__ void __launch_bounds__(256) build_table_kernel(
        const float* __restrict__ W1, const float* __restrict__ b1,
        const float* __restrict__ W2, float2* __restrict__ tab) {
    const int idx = blockIdx.x * 256 + threadIdx.x;
    if (idx >= TDIM * TDIM) return;
    const int iy = idx >> 9;
    const int ix = idx & (TDIM - 1);
    const float vy  = fmaf((float)iy, TSTEP, -6.25f);
    const float vx0 = fmaf((float)ix, TSTEP, -6.25f);
    const float vx1 = fmaf((float)min(ix + 1, TDIM - 1), TSTEP, -6.25f);
    float s0 = 0.0f, s1 = 0.0f;
    #pragma unroll
    for (int k = 0; k < ATT; ++k) {
        const float w1x = W1[k], w1y = W1[ATT + k], bb = b1[k], w2 = W2[k];
        s0 = fmaf(gelu_exact(fmaf(vx0, w1x, fmaf(vy, w1y, bb))), w2, s0);
        s1 = fmaf(gelu_exact(fmaf(vx1, w1x, fmaf(vy, w1y, bb))), w2, s1);
    }
    tab[idx] = make_float2(s0, s1);
}

// ---------------- K1: per-block bucket histogram ---------------------------
__global__ void __launch_bounds__(256) hist_kernel(const int* __restrict__ row,
                                                   int E, int B,
                                                   unsigned* __restrict__ counts /*[B][NBLK]*/) {
    __shared__ unsigned h[MAXB];
    for (int i = threadIdx.x; i < B; i += 256) h[i] = 0u;
    __syncthreads();
    const int T = gridDim.x * 256;
    const int nv = E >> 2;
    const int4* row4 = (const int4*)row;
    for (int i = blockIdx.x * 256 + threadIdx.x; i < nv; i += T) {
        const int4 r = row4[i];
        atomicAdd(&h[((unsigned)r.x) >> LOG_NPB], 1u);
        atomicAdd(&h[((unsigned)r.y) >> LOG_NPB], 1u);
        atomicAdd(&h[((unsigned)r.z) >> LOG_NPB], 1u);
        atomicAdd(&h[((unsigned)r.w) >> LOG_NPB], 1u);
    }
    for (int e = (nv << 2) + blockIdx.x * 256 + threadIdx.x; e < E; e += T)
        atomicAdd(&h[((unsigned)row[e]) >> LOG_NPB], 1u);
    __syncthreads();
    for (int i = threadIdx.x; i < B; i += 256)
        counts[(size_t)i * gridDim.x + blockIdx.x] = h[i];
}

// ---------------- K2a: exclusive scan of each bucket's NBLK counts ---------
// NBLK = 512, 256 threads, exactly 2 elems/thread.
__global__ void __launch_bounds__(256) scan_blocks_kernel(const unsigned* __restrict__ counts,
                                                          unsigned* __restrict__ within,
                                                          unsigned* __restrict__ totals) {
    const int b = blockIdx.x;
    const unsigned* src = counts + (size_t)b * NBLK;
    unsigned* dst = within + (size_t)b * NBLK;
    __shared__ unsigned s[256];
    unsigned v0, v1;
    {
        const uint2 v = ((const uint2*)src)[threadIdx.x];
        v0 = v.x; v1 = v.y;
    }
    s[threadIdx.x] = v0 + v1;
    __syncthreads();
    for (int off = 1; off < 256; off <<= 1) {
        unsigned t = (threadIdx.x >= off) ? s[threadIdx.x - off] : 0u;
        __syncthreads();
        s[threadIdx.x] += t;
        __syncthreads();
    }
    unsigned base = (threadIdx.x > 0) ? s[threadIdx.x - 1] : 0u;
    uint2 o;
    o.x = base; o.y = base + v0;
    ((uint2*)dst)[threadIdx.x] = o;
    if (threadIdx.x == 255) totals[b] = s[255];
}

// ---------------- K2b: exclusive scan of bucket totals -> base[B+1] --------
__global__ void __launch_bounds__(256) scan_totals_kernel(const unsigned* __restrict__ totals,
                                                          unsigned* __restrict__ base, int B) {
    __shared__ unsigned s[256];
    unsigned vals[8];
    const int i0 = threadIdx.x * 8;
    unsigned sum = 0u;
    #pragma unroll
    for (int k = 0; k < 8; ++k) {
        vals[k] = (i0 + k < B) ? totals[i0 + k] : 0u;
        sum += vals[k];
    }
    s[threadIdx.x] = sum;
    __syncthreads();
    for (int off = 1; off < 256; off <<= 1) {
        unsigned t = (threadIdx.x >= off) ? s[threadIdx.x - off] : 0u;
        __syncthreads();
        s[threadIdx.x] += t;
        __syncthreads();
    }
    unsigned b0 = (threadIdx.x > 0) ? s[threadIdx.x - 1] : 0u;
    #pragma unroll
    for (int k = 0; k < 8; ++k) {
        if (i0 + k < B) base[i0 + k] = b0;
        b0 += vals[k];
    }
    if (threadIdx.x == 255) base[B] = s[255];
}

// ---------------- K3: scatter edges into bucket-sorted payload -------------
// payload word: (lrow:11 << 21) | col:21   (V <= 2^21)
__global__ void __launch_bounds__(256) scatter_kernel(const int* __restrict__ row,
                                                      const int* __restrict__ col,
                                                      int E, int B,
                                                      const unsigned* __restrict__ base,
                                                      const unsigned* __restrict__ within,
                                                      unsigned* __restrict__ payload) {
    __shared__ unsigned cur[MAXB];
    const int nblk = gridDim.x;
    for (int i = threadIdx.x; i < B; i += 256)
        cur[i] = base[i] + within[(size_t)i * nblk + blockIdx.x];
    __syncthreads();
    const int T = nblk * 256;
    const int nv = E >> 2;
    const int4* row4 = (const int4*)row;
    const int4* col4 = (const int4*)col;
    for (int i = blockIdx.x * 256 + threadIdx.x; i < nv; i += T) {
        const int4 r = row4[i];
        const int4 c = col4[i];
        {
            const unsigned rr = (unsigned)r.x;
            const unsigned pos = atomicAdd(&cur[rr >> LOG_NPB], 1u);
            payload[pos] = ((rr & (NPB - 1)) << 21) | (unsigned)c.x;
        }
        {
            const unsigned rr = (unsigned)r.y;
            const unsigned pos = atomicAdd(&cur[rr >> LOG_NPB], 1u);
            payload[pos] = ((rr & (NPB - 1)) << 21) | (unsigned)c.y;
        }
        {
            const unsigned rr = (unsigned)r.z;
            const unsigned pos = atomicAdd(&cur[rr >> LOG_NPB], 1u);
            payload[pos] = ((rr & (NPB - 1)) << 21) | (unsigned)c.z;
        }
        {
            const unsigned rr = (unsigned)r.w;
            const unsigned pos = atomicAdd(&cur[rr >> LOG_NPB], 1u);
            payload[pos] = ((rr & (NPB - 1)) << 21) | (unsigned)c.w;
        }
    }
    for (int e = (nv << 2) + blockIdx.x * 256 + threadIdx.x; e < E; e += T) {
        const unsigned rr = (unsigned)row[e];
        const unsigned pos = atomicAdd(&cur[rr >> LOG_NPB], 1u);
        payload[pos] = ((rr & (NPB - 1)) << 21) | (unsigned)col[e];
    }
}

// ---------------- K4: per-bucket LDS accumulate + node epilogue ------------
__device__ __forceinline__ void edge_single(unsigned p,
        const float2* __restrict__ x, const float2* __restrict__ tab,
        const float2* sxi, float* sden, float* smx, float* smy) {
    const unsigned lrow = p >> 21;
    const unsigned c = p & 0x1FFFFFu;
    const float2 xj = x[c];                      // random gather, L2/LLC
    const float2 xi = sxi[lrow];                 // LDS

    const float ax = -xi.x, ay = -xi.y;
    const float bx = xj.x,  by = xj.y;
    const float a2 = ax * ax + ay * ay;
    const float b2 = bx * bx + by * by;
    const float ab = ax * bx + ay * by;
    const float ca = 1.0f + 2.0f * ab + b2;
    const float cb = 1.0f - a2;
    const float dn = fmaxf(1.0f + 2.0f * ab + a2 * b2, EPSF);
    const float rdn = __fdividef(1.0f, dn);
    const float subx = (ca * ax + cb * bx) * rdn;
    const float suby = (ca * ay + cb * by) * rdn;

    const float n = fmaxf(sqrtf(subx * subx + suby * suby), EPSF);
    const float M = fmaxf(1.0f - (xi.x * xi.x + xi.y * xi.y), EPSF);
    const float scl = M * fast_atanh(fminf(n, MAX_ATANH)) * __fdividef(1.0f, n);
    const float vx = scl * subx;
    const float vy = scl * suby;

    float tx = fmaf(vx, TSCALE, TOFF);
    float ty = fmaf(vy, TSCALE, TOFF);
    tx = fminf(fmaxf(tx, 0.0f), 510.999f);
    ty = fminf(fmaxf(ty, 0.0f), 510.999f);
    const int ix = (int)tx;
    const int iy = (int)ty;
    const float fx = tx - (float)ix;
    const float fy = ty - (float)iy;
    const int baseIdx = (iy << 9) + ix;
    const float2 r0 = tab[baseIdx];
    const float2 r1 = tab[baseIdx + TDIM];
    const float s0 = fmaf(fx, r0.y - r0.x, r0.x);
    const float s1 = fmaf(fx, r1.y - r1.x, r1.x);
    const float s  = fmaf(fy, s1 - s0, s0);

    const float ee = __expf(s);
    atomicAdd(&sden[lrow], ee);
    atomicAdd(&smx[lrow], ee * vx);
    atomicAdd(&smy[lrow], ee * vy);
}

__global__ void __launch_bounds__(512, 8) bucket_reduce_kernel(
        const float2* __restrict__ x,
        const float2* __restrict__ tab,
        const unsigned* __restrict__ base,
        const unsigned* __restrict__ payload,
        const int* __restrict__ depth,
        const float* __restrict__ depth_scale,
        const float* __restrict__ depth_theta,
        const float* __restrict__ eta_p,
        float2* __restrict__ out, int V) {
    __shared__ float  sden[NPB];
    __shared__ float  smx[NPB];
    __shared__ float  smy[NPB];
    __shared__ float2 sxi[NPB];
    const int b = blockIdx.x;
    const int nodeBase = b << LOG_NPB;
    for (int i = threadIdx.x; i < NPB; i += 512) {
        sden[i] = 0.f; smx[i] = 0.f; smy[i] = 0.f;
        sxi[i] = x[nodeBase + i];
    }
    __syncthreads();

    // simple scalar grid-stride loop (R6 form): compiler pipelines across
    // iterations; manual pair/quad batching measured slower (R8/R9).
    const unsigned e0 = base[b], e1 = base[b + 1];
    for (unsigned e = e0 + threadIdx.x; e < e1; e += 512)
        edge_single(payload[e], x, tab, sxi, sden, smx, smy);
    __syncthreads();

    // node epilogue: normalize, depth mixer, exp-map
    const float eta = eta_p[0];
    for (int i = threadIdx.x; i < NPB; i += 512) {
        const int v = nodeBase + i;
        if (v >= V) break;
        const float rdv = __fdividef(1.0f, fmaxf(sden[i], EPSF));
        const float mx = smx[i] * rdv;
        const float my = smy[i] * rdv;

        const int d = min(depth[v], 511);
        const float k   = depth_scale[d];
        const float ang = depth_theta[d];
        const float cs = __cosf(ang), sn = __sinf(ang);
        const float m0 = eta * (k * (cs * mx - sn * my));
        const float m1 = eta * (k * (sn * mx + cs * my));

        const float2 xi = sxi[i];

        const float n = fmaxf(sqrtf(m0 * m0 + m1 * m1), EPSF);
        const float M = fmaxf(1.0f - (xi.x * xi.x + xi.y * xi.y), EPSF);
        const float t = fast_tanh(__fdividef(n, M));
        const float tn = t * __fdividef(1.0f, n);
        const float bx = tn * m0;
        const float by = tn * m1;

        const float a2 = xi.x * xi.x + xi.y * xi.y;
        const float b2 = bx * bx + by * by;
        const float ab = xi.x * bx + xi.y * by;
        const float ca = 1.0f + 2.0f * ab + b2;
        const float cb = 1.0f - a2;
        const float dn = fmaxf(1.0f + 2.0f * ab + a2 * b2, EPSF);
        const float rdn = __fdividef(1.0f, dn);

        out[v] = make_float2((ca * xi.x + cb * bx) * rdn,
                             (ca * xi.y + cb * by) * rdn);
    }
}

extern "C" void kernel_launch(void* const* d_in, const int* in_sizes, int n_in,
                              void* d_out, int out_size, void* d_ws, size_t ws_size,
                              hipStream_t stream) {
    const float2* x          = (const float2*)d_in[0];
    const float*  W1         = (const float*)d_in[1];
    const float*  b1         = (const float*)d_in[2];
    const float*  W2         = (const float*)d_in[3];
    const float*  eta        = (const float*)d_in[4];
    const float*  dscale     = (const float*)d_in[5];
    const float*  dtheta     = (const float*)d_in[6];
    const int*    edge_index = (const int*)d_in[7];
    const int*    depth      = (const int*)d_in[8];

    const int V = in_sizes[0] / 2;
    const int E = in_sizes[7] / 2;
    const int B = (V + NPB - 1) >> LOG_NPB;       // 1024 for V = 2^21

    const int* row = edge_index;
    const int* col = edge_index + E;

    // workspace layout (all u32): payload[E] | counts[B*NBLK] | within[B*NBLK]
    //                             | totals[B] | base[B+1]
    // score table (2MB float2) reuses `within` (dead after scatter).
    unsigned* payload = (unsigned*)d_ws;
    unsigned* counts  = payload + E;
    unsigned* within  = counts + (size_t)B * NBLK;
    unsigned* totals  = within + (size_t)B * NBLK;
    unsigned* base    = totals + B;
    float2*   tab     = (float2*)within;

    hist_kernel<<<NBLK, 256, 0, stream>>>(row, E, B, counts);
    scan_blocks_kernel<<<B, 256, 0, stream>>>(counts, within, totals);
    scan_totals_kernel<<<1, 256, 0, stream>>>(totals, base, B);
    scatter_kernel<<<NBLK, 256, 0, stream>>>(row, col, E, B, base, within, payload);
    build_table_kernel<<<(TDIM * TDIM) / 256, 256, 0, stream>>>(W1, b1, W2, tab);
    bucket_reduce_kernel<<<B, 512, 0, stream>>>(x, tab, base, payload,
                                                depth, dscale, dtheta, eta,
                                                (float2*)d_out, V);
}

// Round 11
// 261.618 us; speedup vs baseline: 1.3702x; 1.0022x over previous
//
#include <hip/hip_runtime.h>
#include <math.h>

#define EPSF 1e-15f
#define MAX_ATANH (1.0f - 1e-5f)
#define ATT 16

#define LOG_NPB 11                 // scatter: nodes per bucket = 2048
#define NPB (1 << LOG_NPB)
#define MAXB 1024                  // max scatter buckets (V <= 2^21)
#define NBLK 512                   // blocks in hist/scatter kernels
#define NPR 1024                   // reduce: nodes per block (half bucket)

// score table: s(vx, vy) on [-6.25, 6.25]^2, 512x512, bilinear
#define TDIM 512
#define TSPAN 12.5f
#define TSTEP (TSPAN / (float)(TDIM - 1))
#define TSCALE ((float)(TDIM - 1) / TSPAN)
#define TOFF (6.25f * TSCALE)

// ---- fast branch-free transcendentals --------------------------------------
__device__ __forceinline__ float fast_atanh(float z) {
    return 0.5f * __logf(__fdividef(1.0f + z, 1.0f - z));
}
__device__ __forceinline__ float fast_tanh(float z) {
    return 1.0f - __fdividef(2.0f, __expf(2.0f * z) + 1.0f);
}
__device__ __forceinline__ float gelu_exact(float u) {
    return 0.5f * u * (1.0f + erff(u * 0.70710678118654752f));
}

// ---------------- K0: build score table (exact erf; ~µs) -------------------
__global__ void __launch_bounds__(256) build_table_kernel(
        const float* __restrict__ W1, const float* __restrict__ b1,
        const float* __restrict__ W2, float2* __restrict__ tab) {
    const int idx = blockIdx.x * 256 + threadIdx.x;
    if (idx >= TDIM * TDIM) return;
    const int iy = idx >> 9;
    const int ix = idx & (TDIM - 1);
    const float vy  = fmaf((float)iy, TSTEP, -6.25f);
    const float vx0 = fmaf((float)ix, TSTEP, -6.25f);
    const float vx1 = fmaf((float)min(ix + 1, TDIM - 1), TSTEP, -6.25f);
    float s0 = 0.0f, s1 = 0.0f;
    #pragma unroll
    for (int k = 0; k < ATT; ++k) {
        const float w1x = W1[k], w1y = W1[ATT + k], bb = b1[k], w2 = W2[k];
        s0 = fmaf(gelu_exact(fmaf(vx0, w1x, fmaf(vy, w1y, bb))), w2, s0);
        s1 = fmaf(gelu_exact(fmaf(vx1, w1x, fmaf(vy, w1y, bb))), w2, s1);
    }
    tab[idx] = make_float2(s0, s1);
}

// ---------------- K1: per-block bucket histogram ---------------------------
__global__ void __launch_bounds__(256) hist_kernel(const int* __restrict__ row,
                                                   int E, int B,
                                                   unsigned* __restrict__ counts /*[B][NBLK]*/) {
    __shared__ unsigned h[MAXB];
    for (int i = threadIdx.x; i < B; i += 256) h[i] = 0u;
    __syncthreads();
    const int T = gridDim.x * 256;
    const int nv = E >> 2;
    const int4* row4 = (const int4*)row;
    for (int i = blockIdx.x * 256 + threadIdx.x; i < nv; i += T) {
        const int4 r = row4[i];
        atomicAdd(&h[((unsigned)r.x) >> LOG_NPB], 1u);
        atomicAdd(&h[((unsigned)r.y) >> LOG_NPB], 1u);
        atomicAdd(&h[((unsigned)r.z) >> LOG_NPB], 1u);
        atomicAdd(&h[((unsigned)r.w) >> LOG_NPB], 1u);
    }
    for (int e = (nv << 2) + blockIdx.x * 256 + threadIdx.x; e < E; e += T)
        atomicAdd(&h[((unsigned)row[e]) >> LOG_NPB], 1u);
    __syncthreads();
    for (int i = threadIdx.x; i < B; i += 256)
        counts[(size_t)i * gridDim.x + blockIdx.x] = h[i];
}

// ---------------- K2a: exclusive scan of each bucket's NBLK counts ---------
// NBLK = 512, 256 threads, exactly 2 elems/thread.
__global__ void __launch_bounds__(256) scan_blocks_kernel(const unsigned* __restrict__ counts,
                                                          unsigned* __restrict__ within,
                                                          unsigned* __restrict__ totals) {
    const int b = blockIdx.x;
    const unsigned* src = counts + (size_t)b * NBLK;
    unsigned* dst = within + (size_t)b * NBLK;
    __shared__ unsigned s[256];
    unsigned v0, v1;
    {
        const uint2 v = ((const uint2*)src)[threadIdx.x];
        v0 = v.x; v1 = v.y;
    }
    s[threadIdx.x] = v0 + v1;
    __syncthreads();
    for (int off = 1; off < 256; off <<= 1) {
        unsigned t = (threadIdx.x >= off) ? s[threadIdx.x - off] : 0u;
        __syncthreads();
        s[threadIdx.x] += t;
        __syncthreads();
    }
    unsigned base = (threadIdx.x > 0) ? s[threadIdx.x - 1] : 0u;
    uint2 o;
    o.x = base; o.y = base + v0;
    ((uint2*)dst)[threadIdx.x] = o;
    if (threadIdx.x == 255) totals[b] = s[255];
}

// ---------------- K2b: exclusive scan of bucket totals -> base[B+1] --------
__global__ void __launch_bounds__(256) scan_totals_kernel(const unsigned* __restrict__ totals,
                                                          unsigned* __restrict__ base, int B) {
    __shared__ unsigned s[256];
    unsigned vals[8];
    const int i0 = threadIdx.x * 8;
    unsigned sum = 0u;
    #pragma unroll
    for (int k = 0; k < 8; ++k) {
        vals[k] = (i0 + k < B) ? totals[i0 + k] : 0u;
        sum += vals[k];
    }
    s[threadIdx.x] = sum;
    __syncthreads();
    for (int off = 1; off < 256; off <<= 1) {
        unsigned t = (threadIdx.x >= off) ? s[threadIdx.x - off] : 0u;
        __syncthreads();
        s[threadIdx.x] += t;
        __syncthreads();
    }
    unsigned b0 = (threadIdx.x > 0) ? s[threadIdx.x - 1] : 0u;
    #pragma unroll
    for (int k = 0; k < 8; ++k) {
        if (i0 + k < B) base[i0 + k] = b0;
        b0 += vals[k];
    }
    if (threadIdx.x == 255) base[B] = s[255];
}

// ---------------- K3: scatter edges into bucket-sorted payload -------------
// payload word: (lrow:11 << 21) | col:21   (V <= 2^21); bit31 = upper half
__global__ void __launch_bounds__(256) scatter_kernel(const int* __restrict__ row,
                                                      const int* __restrict__ col,
                                                      int E, int B,
                                                      const unsigned* __restrict__ base,
                                                      const unsigned* __restrict__ within,
                                                      unsigned* __restrict__ payload) {
    __shared__ unsigned cur[MAXB];
    const int nblk = gridDim.x;
    for (int i = threadIdx.x; i < B; i += 256)
        cur[i] = base[i] + within[(size_t)i * nblk + blockIdx.x];
    __syncthreads();
    const int T = nblk * 256;
    const int nv = E >> 2;
    const int4* row4 = (const int4*)row;
    const int4* col4 = (const int4*)col;
    for (int i = blockIdx.x * 256 + threadIdx.x; i < nv; i += T) {
        const int4 r = row4[i];
        const int4 c = col4[i];
        {
            const unsigned rr = (unsigned)r.x;
            const unsigned pos = atomicAdd(&cur[rr >> LOG_NPB], 1u);
            payload[pos] = ((rr & (NPB - 1)) << 21) | (unsigned)c.x;
        }
        {
            const unsigned rr = (unsigned)r.y;
            const unsigned pos = atomicAdd(&cur[rr >> LOG_NPB], 1u);
            payload[pos] = ((rr & (NPB - 1)) << 21) | (unsigned)c.y;
        }
        {
            const unsigned rr = (unsigned)r.z;
            const unsigned pos = atomicAdd(&cur[rr >> LOG_NPB], 1u);
            payload[pos] = ((rr & (NPB - 1)) << 21) | (unsigned)c.z;
        }
        {
            const unsigned rr = (unsigned)r.w;
            const unsigned pos = atomicAdd(&cur[rr >> LOG_NPB], 1u);
            payload[pos] = ((rr & (NPB - 1)) << 21) | (unsigned)c.w;
        }
    }
    for (int e = (nv << 2) + blockIdx.x * 256 + threadIdx.x; e < E; e += T) {
        const unsigned rr = (unsigned)row[e];
        const unsigned pos = atomicAdd(&cur[rr >> LOG_NPB], 1u);
        payload[pos] = ((rr & (NPB - 1)) << 21) | (unsigned)col[e];
    }
}

// ---------------- K4: per-half-bucket LDS accumulate + node epilogue -------
// 2048 blocks; block = (scatter bucket bkt = blockIdx>>1, half hb = blockIdx&1).
// Scans bucket's edges, processes only those whose payload bit31 == hb.
__device__ __forceinline__ void edge_single(unsigned p,
        const float2* __restrict__ x, const float2* __restrict__ tab,
        const float2* sxi, float* sden, float* smx, float* smy) {
    const unsigned lrow = (p >> 21) & (NPR - 1);   // index within half
    const unsigned c = p & 0x1FFFFFu;
    const float2 xj = x[c];                      // random gather, L2/LLC
    const float2 xi = sxi[lrow];                 // LDS

    const float ax = -xi.x, ay = -xi.y;
    const float bx = xj.x,  by = xj.y;
    const float a2 = ax * ax + ay * ay;
    const float b2 = bx * bx + by * by;
    const float ab = ax * bx + ay * by;
    const float ca = 1.0f + 2.0f * ab + b2;
    const float cb = 1.0f - a2;
    const float dn = fmaxf(1.0f + 2.0f * ab + a2 * b2, EPSF);
    const float rdn = __fdividef(1.0f, dn);
    const float subx = (ca * ax + cb * bx) * rdn;
    const float suby = (ca * ay + cb * by) * rdn;

    const float n = fmaxf(sqrtf(subx * subx + suby * suby), EPSF);
    const float M = fmaxf(1.0f - (xi.x * xi.x + xi.y * xi.y), EPSF);
    const float scl = M * fast_atanh(fminf(n, MAX_ATANH)) * __fdividef(1.0f, n);
    const float vx = scl * subx;
    const float vy = scl * suby;

    float tx = fmaf(vx, TSCALE, TOFF);
    float ty = fmaf(vy, TSCALE, TOFF);
    tx = fminf(fmaxf(tx, 0.0f), 510.999f);
    ty = fminf(fmaxf(ty, 0.0f), 510.999f);
    const int ix = (int)tx;
    const int iy = (int)ty;
    const float fx = tx - (float)ix;
    const float fy = ty - (float)iy;
    const int baseIdx = (iy << 9) + ix;
    const float2 r0 = tab[baseIdx];
    const float2 r1 = tab[baseIdx + TDIM];
    const float s0 = fmaf(fx, r0.y - r0.x, r0.x);
    const float s1 = fmaf(fx, r1.y - r1.x, r1.x);
    const float s  = fmaf(fy, s1 - s0, s0);

    const float ee = __expf(s);
    atomicAdd(&sden[lrow], ee);
    atomicAdd(&smx[lrow], ee * vx);
    atomicAdd(&smy[lrow], ee * vy);
}

__global__ void __launch_bounds__(512, 8) bucket_reduce_kernel(
        const float2* __restrict__ x,
        const float2* __restrict__ tab,
        const unsigned* __restrict__ base,
        const unsigned* __restrict__ payload,
        const int* __restrict__ depth,
        const float* __restrict__ depth_scale,
        const float* __restrict__ depth_theta,
        const float* __restrict__ eta_p,
        float2* __restrict__ out, int V) {
    __shared__ float  sden[NPR];
    __shared__ float  smx[NPR];
    __shared__ float  smy[NPR];
    __shared__ float2 sxi[NPR];
    const int bkt = blockIdx.x >> 1;               // scatter bucket
    const unsigned hb = blockIdx.x & 1;            // half (0=low, 1=high)
    const int nodeBase = (bkt << LOG_NPB) + ((int)hb << 10);
    for (int i = threadIdx.x; i < NPR; i += 512) {
        sden[i] = 0.f; smx[i] = 0.f; smy[i] = 0.f;
        sxi[i] = x[nodeBase + i];
    }
    __syncthreads();

    // scan the full bucket edge range; predicate on the half bit (payload
    // bit31). ~50% lanes active in edge math — VALU has headroom (22% busy).
    const unsigned e0 = base[bkt], e1 = base[bkt + 1];
    for (unsigned e = e0 + threadIdx.x; e < e1; e += 512) {
        const unsigned p = payload[e];
        if ((p >> 31) == hb)
            edge_single(p, x, tab, sxi, sden, smx, smy);
    }
    __syncthreads();

    // node epilogue: normalize, depth mixer, exp-map
    const float eta = eta_p[0];
    for (int i = threadIdx.x; i < NPR; i += 512) {
        const int v = nodeBase + i;
        if (v >= V) break;
        const float rdv = __fdividef(1.0f, fmaxf(sden[i], EPSF));
        const float mx = smx[i] * rdv;
        const float my = smy[i] * rdv;

        const int d = min(depth[v], 511);
        const float k   = depth_scale[d];
        const float ang = depth_theta[d];
        const float cs = __cosf(ang), sn = __sinf(ang);
        const float m0 = eta * (k * (cs * mx - sn * my));
        const float m1 = eta * (k * (sn * mx + cs * my));

        const float2 xi = sxi[i];

        const float n = fmaxf(sqrtf(m0 * m0 + m1 * m1), EPSF);
        const float M = fmaxf(1.0f - (xi.x * xi.x + xi.y * xi.y), EPSF);
        const float t = fast_tanh(__fdividef(n, M));
        const float tn = t * __fdividef(1.0f, n);
        const float bx = tn * m0;
        const float by = tn * m1;

        const float a2 = xi.x * xi.x + xi.y * xi.y;
        const float b2 = bx * bx + by * by;
        const float ab = xi.x * bx + xi.y * by;
        const float ca = 1.0f + 2.0f * ab + b2;
        const float cb = 1.0f - a2;
        const float dn = fmaxf(1.0f + 2.0f * ab + a2 * b2, EPSF);
        const float rdn = __fdividef(1.0f, dn);

        out[v] = make_float2((ca * xi.x + cb * bx) * rdn,
                             (ca * xi.y + cb * by) * rdn);
    }
}

extern "C" void kernel_launch(void* const* d_in, const int* in_sizes, int n_in,
                              void* d_out, int out_size, void* d_ws, size_t ws_size,
                              hipStream_t stream) {
    const float2* x          = (const float2*)d_in[0];
    const float*  W1         = (const float*)d_in[1];
    const float*  b1         = (const float*)d_in[2];
    const float*  W2         = (const float*)d_in[3];
    const float*  eta        = (const float*)d_in[4];
    const float*  dscale     = (const float*)d_in[5];
    const float*  dtheta     = (const float*)d_in[6];
    const int*    edge_index = (const int*)d_in[7];
    const int*    depth      = (const int*)d_in[8];

    const int V = in_sizes[0] / 2;
    const int E = in_sizes[7] / 2;
    const int B = (V + NPB - 1) >> LOG_NPB;       // 1024 scatter buckets

    const int* row = edge_index;
    const int* col = edge_index + E;

    // workspace layout (all u32): payload[E] | counts[B*NBLK] | within[B*NBLK]
    //                             | totals[B] | base[B+1]
    // score table (2MB float2) reuses `within` (dead after scatter).
    unsigned* payload = (unsigned*)d_ws;
    unsigned* counts  = payload + E;
    unsigned* within  = counts + (size_t)B * NBLK;
    unsigned* totals  = within + (size_t)B * NBLK;
    unsigned* base    = totals + B;
    float2*   tab     = (float2*)within;

    hist_kernel<<<NBLK, 256, 0, stream>>>(row, E, B, counts);
    scan_blocks_kernel<<<B, 256, 0, stream>>>(counts, within, totals);
    scan_totals_kernel<<<1, 256, 0, stream>>>(totals, base, B);
    scatter_kernel<<<NBLK, 256, 0, stream>>>(row, col, E, B, base, within, payload);
    build_table_kernel<<<(TDIM * TDIM) / 256, 256, 0, stream>>>(W1, b1, W2, tab);
    bucket_reduce_kernel<<<2 * B, 512, 0, stream>>>(x, tab, base, payload,
                                                    depth, dscale, dtheta, eta,
                                                    (float2*)d_out, V);
}